// Round 8
// baseline (520.689 us; speedup 1.0000x reference)
//
#include <hip/hip_runtime.h>

#define IN_SIZE 256
#define OUT_SIZE 64
#define N_NODES 512
#define FAN_IN 32
#define T_DIM 2048
#define D_DIM 832
#define TOTAL_EDGE 16384
#define BLK_F4 1088   // per-node: 1024 f4 butterfly pairs + 64 f4 entries
#define MAX_ENT 64
#define THRESH -20.0f
#define RING 6
#define GROUP 3
#define BLKROWS 17    // 1088 f4 = 17 rows x 64 lanes x 16 B

// s_waitcnt: vmcnt<=N only. gfx9 encoding: [3:0]=vm lo,[6:4]=exp,[11:8]=lgkm,[15:14]=vm hi
#define WAITVM(N)                                                       \
  __builtin_amdgcn_s_waitcnt(((N) & 0xF) | (((N) >> 4) << 14) |         \
                             (0xF << 8) | (0x7 << 4))

typedef const __attribute__((address_space(1))) void gas_t;
typedef __attribute__((address_space(3))) void las_t;

__device__ __forceinline__ void lds_dma16(const float4* g, const float4* l,
                                          int lane) {
  __builtin_amdgcn_global_load_lds((gas_t*)(g + lane), (las_t*)l, 16, 0, 0);
}

// DPP wave64 sum (lane 63 ends with total) — validated rounds 3..7
template <int CTRL, int RM>
__device__ __forceinline__ float dppadd(float v) {
  int m = __builtin_amdgcn_update_dpp(0, __float_as_int(v), CTRL, RM, 0xf, true);
  return v + __int_as_float(m);
}
__device__ __forceinline__ void wave_sum2(float& a, float& b) {
  a = dppadd<0x111, 0xf>(a); b = dppadd<0x111, 0xf>(b);
  a = dppadd<0x112, 0xf>(a); b = dppadd<0x112, 0xf>(b);
  a = dppadd<0x114, 0xf>(a); b = dppadd<0x114, 0xf>(b);
  a = dppadd<0x118, 0xf>(a); b = dppadd<0x118, 0xf>(b);
  a = dppadd<0x142, 0xa>(a); b = dppadd<0x142, 0xa>(b);
  a = dppadd<0x143, 0xc>(a); b = dppadd<0x143, 0xc>(b);
}
__device__ __forceinline__ float rl63(float v) {
  return __int_as_float(__builtin_amdgcn_readlane(__float_as_int(v), 63));
}

// ---------------------------------------------------------------------------
// KV build (t-major, rows staged in LDS). 512 blocks x 4 t-rows (2 blocks/CU
// for latency overlap). Writes (k,v) t-order into blk KV area; slot 2047 = 0.
// ---------------------------------------------------------------------------
__global__ __launch_bounds__(256) void kv_kernel(
    const float* __restrict__ actives, const int* __restrict__ in_idxs,
    const float* __restrict__ weights, float2* __restrict__ KVd) {
  __shared__ float rows[4][833];
  __shared__ int s_idx[64 * FAN_IN];
  __shared__ float2 s_w[64 * FAN_IN];
  int tid = threadIdx.x;
  int tb = blockIdx.x * 4;
  for (int i = tid; i < 4 * D_DIM; i += 256) {
    int r = i / D_DIM, c = i - r * D_DIM;
    int t = tb + r;
    rows[r][c] = (t < T_DIM - 1) ? actives[(size_t)(t + 1) * D_DIM + c] : 0.f;
  }
  int tl = tid & 3, ng = tid >> 2;  // 4 t x 64 nodes
  for (int tile = 0; tile < 8; ++tile) {
    __syncthreads();
    int n0 = tile * 64;
    for (int i = tid; i < 64 * FAN_IN; i += 256) {
      int g = n0 * FAN_IN + i;
      s_idx[i] = in_idxs[g];
      const float* wp = weights + (size_t)g * 3;
      s_w[i] = make_float2(wp[1], wp[2]);
    }
    __syncthreads();
    const int* ip = &s_idx[ng * FAN_IN];
    const float2* wp = &s_w[ng * FAN_IN];
    float k = 0.f, v = 0.f;
#pragma unroll 8
    for (int f = 0; f < FAN_IN; ++f) {
      float a = rows[tl][ip[f]];
      float2 w = wp[f];
      k = fmaf(w.x, a, k);
      v = fmaf(w.y, a, v);
    }
    KVd[(size_t)(n0 + ng) * (2 * BLK_F4) + tb + tl] = make_float2(k, v);
  }
}

// ---------------------------------------------------------------------------
// Block build: bucket-sort k ascending -> butterfly pairs
// B[p] = (asc_k, asc_v, desc_k, desc_v) p<1024; entries at B[1024..1087];
// meta (kmax/kmin/cnt/skip-bounds/adj) -> meta_g; base dot -> Qb.
// Self-built consumer entry list (scan in_idxs; d>=2 consumers only).
// ---------------------------------------------------------------------------
__global__ __launch_bounds__(256) void block_kernel(
    const float* __restrict__ x, const int* __restrict__ in_idxs,
    const float* __restrict__ weights, float4* __restrict__ blk,
    float4* __restrict__ meta_g, float4* __restrict__ Qb) {
  __shared__ float2 skv[T_DIM], sbk[T_DIM];
  __shared__ int hist[64];
  __shared__ float smx[4], smn[4];
  __shared__ float sadj[3];
  __shared__ float4 sEnt[MAX_ENT];
  __shared__ int ecnt;
  int node = blockIdx.x, tid = threadIdx.x;
  if (tid == 0) ecnt = 0;
  const float2* src = (const float2*)(blk + (size_t)node * BLK_F4);
  float mx = -3.4e38f, mn = 3.4e38f;
#pragma unroll
  for (int j = 0; j < 8; ++j) {
    int t = j * 256 + tid;
    float2 kv = (t < 2047) ? src[t] : make_float2(0.f, 0.f);
    skv[t] = kv;
    if (t < 2047) { mx = fmaxf(mx, kv.x); mn = fminf(mn, kv.x); }
  }
  if (tid < 64) hist[tid] = 0;
#pragma unroll
  for (int off = 32; off > 0; off >>= 1) {
    mx = fmaxf(mx, __shfl_xor(mx, off));
    mn = fminf(mn, __shfl_xor(mn, off));
  }
  if ((tid & 63) == 0) { smx[tid >> 6] = mx; smn[tid >> 6] = mn; }
  __syncthreads();
  float kmax = fmaxf(fmaxf(smx[0], smx[1]), fmaxf(smx[2], smx[3]));
  float kmin = fminf(fminf(smn[0], smn[1]), fminf(smn[2], smn[3]));
  float invbw = 64.0f / (kmax - kmin);
#pragma unroll
  for (int j = 0; j < 8; ++j) {
    int t = j * 256 + tid;
    if (t < 2047) {
      int b = (int)((skv[t].x - kmin) * invbw);
      b = b < 0 ? 0 : (b > 63 ? 63 : b);
      atomicAdd(&hist[b], 1);
    }
  }
  // consumer entries: edges e with in_idxs[e]==256+node, consumer != node+1
  {
    int target = IN_SIZE + node;
    for (int e = tid; e < TOTAL_EDGE; e += 256) {
      if (in_idxs[e] == target) {
        int c = e >> 5;
        if (c != node + 1) {
          int p = atomicAdd(&ecnt, 1);
          if (p < MAX_ENT) {
            const float* wp = weights + (size_t)e * 3;
            sEnt[p] = make_float4(__int_as_float(c), wp[0], wp[1], wp[2]);
          }
        }
      }
    }
  }
  __syncthreads();
  if (tid < 64) {
    int v = hist[tid];
    int incl = v;
#pragma unroll
    for (int d = 1; d < 64; d <<= 1) {
      int u = __shfl_up(incl, d);
      if (tid >= d) incl += u;
    }
    hist[tid] = incl - v;
  }
  if (tid == 0) sbk[2047] = make_float2(0.f, 0.f);
  __syncthreads();
#pragma unroll
  for (int j = 0; j < 8; ++j) {
    int t = j * 256 + tid;
    if (t < 2047) {
      int b = (int)((skv[t].x - kmin) * invbw);
      b = b < 0 ? 0 : (b > 63 ? 63 : b);
      int p = atomicAdd(&hist[b], 1);
      sbk[p] = skv[t];
    }
  }
  // base dot + d1 patch weights
  if (tid < 32) {
    int g = node * FAN_IN + tid;
    int idx = in_idxs[g];
    const float* wp = weights + (size_t)g * 3;
    float a = (idx < IN_SIZE) ? x[idx] : 0.f;
    bool d1 = (idx >= IN_SIZE) && (idx - IN_SIZE == node - 1);
    float p0 = a * wp[0], p1 = a * wp[1], p2 = a * wp[2];
    float p3 = d1 ? wp[0] : 0.f, p4 = d1 ? wp[1] : 0.f, p5 = d1 ? wp[2] : 0.f;
#pragma unroll
    for (int off = 16; off > 0; off >>= 1) {
      p0 += __shfl_xor(p0, off); p1 += __shfl_xor(p1, off);
      p2 += __shfl_xor(p2, off); p3 += __shfl_xor(p3, off);
      p4 += __shfl_xor(p4, off); p5 += __shfl_xor(p5, off);
    }
    if (tid == 0) {
      Qb[node] = make_float4(p0, p1, p2, 0.f);
      sadj[0] = p3; sadj[1] = p4; sadj[2] = p5;
    }
  }
  __syncthreads();
  float4* B = blk + (size_t)node * BLK_F4;
  for (int i = tid; i < 1024; i += 256) {
    float2 a = sbk[i];
    float2 d = sbk[2046 - i];
    B[i] = make_float4(a.x, a.y, d.x, d.y);
  }
  int cnt = ecnt < MAX_ENT ? ecnt : MAX_ENT;
  if (tid < MAX_ENT)
    B[1024 + tid] = (tid < cnt) ? sEnt[tid] : make_float4(0.f, 0.f, 0.f, 0.f);
  if (tid == 0)
    meta_g[3 * node + 0] =
        make_float4(kmax, kmin, __int_as_float(cnt), sbk[256].x);
  if (tid == 1)
    meta_g[3 * node + 1] =
        make_float4(sbk[1790].x, sbk[512].x, sbk[1534].x, sbk[768].x);
  if (tid == 2)
    meta_g[3 * node + 2] = make_float4(sbk[1278].x, sadj[0], sadj[1], sadj[2]);
}

// ---------------------------------------------------------------------------
// Sequential scan: 2 waves, producer/consumer, zero barriers after init.
// Wave 1: DMA engine — global_load_lds in groups of 3 nodes into a 6-slot
//   LDS ring, vmcnt(0) drain OFF the critical path, release-store progress.
// Wave 0: pure compute — NO global loads / vm waits in its loop. f0+entries
//   pre-read one node ahead from the ring; tail chunks read conditionally.
// ---------------------------------------------------------------------------
__global__ __launch_bounds__(128, 1) void seq_kernel(
    const float4* __restrict__ Qb, const float4* __restrict__ meta_g,
    const float4* __restrict__ blk, float* __restrict__ out) {
  __shared__ float4 sRing[RING * BLK_F4];  // 104448 B
  __shared__ float4 sMeta[N_NODES][3];     // 24576 B
  __shared__ float4 sQKV[N_NODES];         // 8192 B
  __shared__ float souts[OUT_SIZE];
  __shared__ int sProgress, sRelease;
  const int tid = threadIdx.x;
  const int lane = tid & 63;
  const int wid = tid >> 6;
  for (int n = tid; n < N_NODES; n += 128) {
    sMeta[n][0] = meta_g[3 * n + 0];
    sMeta[n][1] = meta_g[3 * n + 1];
    sMeta[n][2] = meta_g[3 * n + 2];
    sQKV[n] = Qb[n];
  }
  if (tid == 0) { sProgress = 0; sRelease = 0; }
  __syncthreads();  // the only barrier

  if (wid == 1) {
    // ---------------- producer ----------------
    int rel = 0;
    for (int g = 0; g < N_NODES; g += GROUP) {
      int limit = g + GROUP - RING;  // need nodes <= limit-1 consumed
      while (rel < limit)
        rel = __hip_atomic_load(&sRelease, __ATOMIC_ACQUIRE,
                                __HIP_MEMORY_SCOPE_WORKGROUP);
#pragma unroll
      for (int k = 0; k < GROUP; ++k) {
        int n = g + k;
        if (n < N_NODES) {
          const float4* gsrc = blk + (size_t)n * BLK_F4;
          const float4* ldst = &sRing[(n % RING) * BLK_F4];
#pragma unroll
          for (int i = 0; i < BLKROWS; ++i)
            lds_dma16(gsrc + i * 64, ldst + i * 64, lane);
        }
      }
      WAITVM(0);  // drain: data resident in ring
      int np = g + GROUP;
      if (np > N_NODES) np = N_NODES;
      __hip_atomic_store(&sProgress, np, __ATOMIC_RELEASE,
                         __HIP_MEMORY_SCOPE_WORKGROUP);
    }
    return;
  }

  // ---------------- consumer (wave 0) ----------------
  int prog = 0;
  while (prog < 1)
    prog = __hip_atomic_load(&sProgress, __ATOMIC_ACQUIRE,
                             __HIP_MEMORY_SCOPE_WORKGROUP);
  float4 f0[4], ent;
  {
    const float4* r0 = &sRing[0];
#pragma unroll
    for (int t = 0; t < 4; ++t) f0[t] = r0[64 * t + lane];
    ent = r0[1024 + lane];
  }
  float4 qkv = sQKV[0];  // node 0: no d1 predecessor -> exact
  float4 mC0 = sMeta[0][0], mC1 = sMeta[0][1], mC2 = sMeta[0][2];

  for (int ix = 0; ix < N_NODES; ++ix) {
    int need = ix + 2;
    if (need > N_NODES) need = N_NODES;
    if (prog < need) {
      do {
        prog = __hip_atomic_load(&sProgress, __ATOMIC_ACQUIRE,
                                 __HIP_MEMORY_SCOPE_WORKGROUP);
      } while (prog < need);
    }
    int ixn = (ix + 1 < N_NODES) ? ix + 1 : N_NODES - 1;
    const float4* rc = &sRing[(ix % RING) * BLK_F4];
    const float4* rn = &sRing[(ixn % RING) * BLK_F4];

    float q = qkv.x, kl = qkv.y, vl = qkv.z;
    int cnt = __float_as_int(mC0.z);
    float m = fmaxf(fmaxf(q * mC0.x, q * mC0.y), q * kl);
    float el = __expf(q * kl - m);
    bool p1 = fmaxf(q * mC0.w, q * mC1.x) - m >= THRESH;
    bool p2 = p1 && (fmaxf(q * mC1.y, q * mC1.z) - m >= THRESH);
    bool p3 = p2 && (fmaxf(q * mC1.w, q * mC2.x) - m >= THRESH);

    // conditional tail-chunk ds_reads (data already DMA'd; ~20% of nodes)
    float4 x1[4], x2[4], x3[4];
    if (p1) {
#pragma unroll
      for (int t = 0; t < 4; ++t) x1[t] = rc[256 + 64 * t + lane];
    }
    if (p2) {
#pragma unroll
      for (int t = 0; t < 4; ++t) x2[t] = rc[512 + 64 * t + lane];
    }
    if (p3) {
#pragma unroll
      for (int t = 0; t < 4; ++t) x3[t] = rc[768 + 64 * t + lane];
    }
    // pre-reads for node ix+1 (latency hidden behind this step's compute)
    float4 rawn = sQKV[ixn];
    float4 mN0 = sMeta[ixn][0], mN1 = sMeta[ixn][1], mN2 = sMeta[ixn][2];
    float4 nf0[4], nent;
#pragma unroll
    for (int t = 0; t < 4; ++t) nf0[t] = rn[64 * t + lane];
    nent = rn[1024 + lane];

    // pair-block 0 from pre-read regs; wrong-direction side underflows
    float swa = 0.f, swb = 0.f, sva = 0.f, svb = 0.f;
#pragma unroll
    for (int t = 0; t < 4; ++t) {
      float w0 = __expf(fmaf(q, f0[t].x, -m));
      float w1 = __expf(fmaf(q, f0[t].z, -m));
      if (t & 1) {
        swb += w0 + w1;
        svb = fmaf(w0, f0[t].y, fmaf(w1, f0[t].w, svb));
      } else {
        swa += w0 + w1;
        sva = fmaf(w0, f0[t].y, fmaf(w1, f0[t].w, sva));
      }
    }
    if (p1) {
#pragma unroll
      for (int t = 0; t < 4; ++t) {
        float w0 = __expf(fmaf(q, x1[t].x, -m));
        float w1 = __expf(fmaf(q, x1[t].z, -m));
        if (t & 1) {
          swb += w0 + w1;
          svb = fmaf(w0, x1[t].y, fmaf(w1, x1[t].w, svb));
        } else {
          swa += w0 + w1;
          sva = fmaf(w0, x1[t].y, fmaf(w1, x1[t].w, sva));
        }
      }
    }
    if (p2) {
#pragma unroll
      for (int t = 0; t < 4; ++t) {
        float w0 = __expf(fmaf(q, x2[t].x, -m));
        float w1 = __expf(fmaf(q, x2[t].z, -m));
        if (t & 1) {
          swb += w0 + w1;
          svb = fmaf(w0, x2[t].y, fmaf(w1, x2[t].w, svb));
        } else {
          swa += w0 + w1;
          sva = fmaf(w0, x2[t].y, fmaf(w1, x2[t].w, sva));
        }
      }
    }
    if (p3) {
#pragma unroll
      for (int t = 0; t < 4; ++t) {
        float w0 = __expf(fmaf(q, x3[t].x, -m));
        float w1 = __expf(fmaf(q, x3[t].z, -m));
        if (t == 3 && lane == 63) w1 = 0.f;  // pair 1023 desc = median dup
        if (t & 1) {
          swb += w0 + w1;
          svb = fmaf(w0, x3[t].y, fmaf(w1, x3[t].w, svb));
        } else {
          swa += w0 + w1;
          sva = fmaf(w0, x3[t].y, fmaf(w1, x3[t].w, sva));
        }
      }
    }

    float sw = swa + swb, swv = sva + svb;
    wave_sum2(sw, swv);
    float S = rl63(sw) + el;
    float SV = fmaf(el, vl, rl63(swv));
    float z = SV * __builtin_amdgcn_rcpf(S);
    float eo = __expf(2.f * z);
    float o = 1.f - 2.f * __builtin_amdgcn_rcpf(eo + 1.f);
    if (lane == 0 && ix >= N_NODES - OUT_SIZE)
      souts[ix - (N_NODES - OUT_SIZE)] = o;

    // scatter o into pending dots (d>=2 consumers; never targets ix+1)
    if (lane < cnt) {
      int n = __float_as_int(ent.x);
      atomicAdd(&sQKV[n].x, o * ent.y);
      atomicAdd(&sQKV[n].y, o * ent.z);
      atomicAdd(&sQKV[n].z, o * ent.w);
    }

    // all ring reads for slot ix%RING done -> free it for the producer
    if (lane == 0)
      __hip_atomic_store(&sRelease, ix + 1, __ATOMIC_RELEASE,
                         __HIP_MEMORY_SCOPE_WORKGROUP);

    // rotate: d1 register patch (adj = mN2.yzw) completes node ix+1's dot
    qkv = make_float4(fmaf(o, mN2.y, rawn.x), fmaf(o, mN2.z, rawn.y),
                      fmaf(o, mN2.w, rawn.z), 0.f);
    mC0 = mN0; mC1 = mN1; mC2 = mN2;
#pragma unroll
    for (int t = 0; t < 4; ++t) f0[t] = nf0[t];
    ent = nent;
  }
  out[lane] = souts[lane];
}

// ---------------------------------------------------------------------------
extern "C" void kernel_launch(void* const* d_in, const int* in_sizes, int n_in,
                              void* d_out, int out_size, void* d_ws,
                              size_t ws_size, hipStream_t stream) {
  const float* x = (const float*)d_in[0];
  const float* actives = (const float*)d_in[1];
  const float* weights = (const float*)d_in[2];
  const int* in_idxs = (const int*)d_in[3];
  float* out = (float*)d_out;

  // workspace (~9.0 MB): blk | meta_g | Qb
  char* ws = (char*)d_ws;
  float4* blk = (float4*)ws;  // 512 * 1088 * 16 = 8,912,896 B
  size_t off = (size_t)N_NODES * BLK_F4 * 16;
  float4* meta_g = (float4*)(ws + off); off += (size_t)N_NODES * 3 * 16;
  float4* Qb = (float4*)(ws + off);

  kv_kernel<<<T_DIM / 4, 256, 0, stream>>>(actives, in_idxs, weights,
                                           (float2*)blk);
  block_kernel<<<N_NODES, 256, 0, stream>>>(x, in_idxs, weights, blk, meta_g,
                                            Qb);
  seq_kernel<<<1, 128, 0, stream>>>(Qb, meta_g, blk, out);
}